// Round 6
// baseline (231.760 us; speedup 1.0000x reference)
//
#include <hip/hip_runtime.h>

#define T_STEPS 512
#define CHUNK   32
#define NCHUNK  (T_STEPS / CHUNK)   // 16
#define EPB     32                  // elements per 256-thread block
#define ROWF    132                 // padded row: 33 float4 = 132 floats (bank-conflict-free)
#define BUFF    (EPB * ROWF)        // 4224 floats per buffer
#define LOG2E   1.4426950408889634f

typedef float v2f __attribute__((ext_vector_type(2)));

// Packed fp32 ops; scalar s broadcast from the LOW half of an undef-high pair
// via op_sel_hi (verified exact in R5).
__device__ __forceinline__ v2f pk_fma_b(v2f w, float s, v2f c) {
    v2f sv; sv.x = s;
    v2f d;
    asm("v_pk_fma_f32 %0, %1, %2, %3 op_sel_hi:[1,0,1]"
        : "=v"(d) : "v"(w), "v"(sv), "v"(c));
    return d;
}
__device__ __forceinline__ void pk_fma_acc(v2f& a, v2f w, float s) {
    v2f sv; sv.x = s;
    asm("v_pk_fma_f32 %0, %1, %2, %0 op_sel_hi:[1,0,1]"
        : "+v"(a) : "v"(w), "v"(sv));
}
__device__ __forceinline__ v2f pk_mul_b(v2f w, float s) {
    v2f sv; sv.x = s;
    v2f d;
    asm("v_pk_mul_f32 %0, %1, %2 op_sel_hi:[1,0]"
        : "=v"(d) : "v"(w), "v"(sv));
    return d;
}
__device__ __forceinline__ v2f pk_add2(v2f a, v2f b) {
    v2f d;
    asm("v_pk_add_f32 %0, %1, %2" : "=v"(d) : "v"(a), "v"(b));
    return d;
}

// Cross-lane xor within the 8-lane group:
//  xor1=quad_perm[1,0,3,2]=0xB1, xor2=[2,3,0,1]=0x4E, xor3=[3,2,1,0]=0x1B,
//  xor7=row_half_mirror=0x141 (DPP, ~2cyc); xor4/5/6 = ds_swizzle BitMode.
template <int CTRL>
__device__ __forceinline__ float dppf(float v) {
    return __int_as_float(__builtin_amdgcn_update_dpp(
        0, __float_as_int(v), CTRL, 0xF, 0xF, true));
}
template <int IMM>
__device__ __forceinline__ float swzf(float v) {
    return __int_as_float(__builtin_amdgcn_ds_swizzle(__float_as_int(v), IMM));
}

// 8 lanes per batch element; lane j owns unit j's 4 gate rows, packed (i,f)/(g,o)
// -> 26 v_pk_fma per step, 10 trans (the true floor), 7 xor exchanges.
// x staged through double-buffered padded LDS tiles: 4 coalesced dwordx4 +
// 4 ds_write_b128 per thread per 32-step chunk; loads pipelined 2 chunks deep
// (cannot be sunk across __syncthreads -> compiler-proof prefetch).
__global__ __launch_bounds__(256, 1) void lstm_kernel(
    const float* __restrict__ x, const float* __restrict__ W_ih,
    const float* __restrict__ W_hh, const float* __restrict__ b_ih,
    const float* __restrict__ b_hh, const float* __restrict__ W_fc,
    const float* __restrict__ b_fc, float* __restrict__ out, int B)
{
    __shared__ float ldsx[2 * BUFF];

    const int tid = threadIdx.x;
    const int e   = tid >> 3;          // block-local element [0,32)
    const int j   = tid & 7;           // hidden unit

    // ---- loop-invariant weights (packed gate pairs; W_hh xor-permuted) ----
    const int ri = j, rf = 8 + j, rg = 16 + j, ro = 24 + j;
    v2f wihIF[4], wihGO[4], whhIF[8], whhGO[8], biasIF, biasGO;
    #pragma unroll
    for (int k = 0; k < 4; ++k) {
        wihIF[k] = v2f{W_ih[ri * 4 + k], W_ih[rf * 4 + k]};
        wihGO[k] = v2f{W_ih[rg * 4 + k], W_ih[ro * 4 + k]};
    }
    #pragma unroll
    for (int s = 0; s < 8; ++s) {
        const int m = j ^ s;           // unit arriving via xor-s exchange
        whhIF[s] = v2f{W_hh[ri * 8 + m], W_hh[rf * 8 + m]};
        whhGO[s] = v2f{W_hh[rg * 8 + m], W_hh[ro * 8 + m]};
    }
    biasIF = v2f{b_ih[ri] + b_hh[ri], b_ih[rf] + b_hh[rf]};
    biasGO = v2f{b_ih[rg] + b_hh[rg], b_ih[ro] + b_hh[ro]};

    // ---- x staging setup: thread covers flat slots tid, tid+256, tid+512, tid+768
    int se[4], st[4];
    const float* gp[4];
    #pragma unroll
    for (int q = 0; q < 4; ++q) {
        const int f = tid + q * 256;
        se[q] = f >> 5;                // element
        st[q] = f & 31;                // step within chunk
        gp[q] = x + (size_t)(blockIdx.x * EPB + se[q]) * (T_STEPS * 4) + st[q] * 4;
    }

    float4 v[4];
    #pragma unroll
    for (int q = 0; q < 4; ++q) v[q] = *(const float4*)(gp[q]);            // chunk 0
    #pragma unroll
    for (int q = 0; q < 4; ++q)
        *(float4*)&ldsx[se[q] * ROWF + st[q] * 4] = v[q];
    #pragma unroll
    for (int q = 0; q < 4; ++q) v[q] = *(const float4*)(gp[q] + CHUNK * 4); // chunk 1
    __syncthreads();

    float h = 0.0f, c = 0.0f;
    const float nL  = -LOG2E;
    const float n2L = -2.0f * LOG2E;

    for (int n = 0; n < NCHUNK; ++n) {
        // publish chunk n+1 (loaded last iteration; regs long since landed)
        const int wb = ((n + 1) & 1) * BUFF;
        #pragma unroll
        for (int q = 0; q < 4; ++q)
            *(float4*)&ldsx[wb + se[q] * ROWF + st[q] * 4] = v[q];
        // fetch chunk n+2 (index wraps; junk on last iters, never consumed)
        const int t2 = ((n + 2) & (NCHUNK - 1)) * (CHUNK * 4);
        #pragma unroll
        for (int q = 0; q < 4; ++q) v[q] = *(const float4*)(gp[q] + t2);

        const float* xr = &ldsx[(n & 1) * BUFF + e * ROWF];
        #pragma unroll
        for (int t = 0; t < CHUNK; ++t) {
            const float4 xt = *(const float4*)(xr + t * 4);   // 8-lane broadcast read

            const float s1 = dppf<0xB1>(h);
            const float s2 = dppf<0x4E>(h);
            const float s3 = dppf<0x1B>(h);
            const float s7 = dppf<0x141>(h);
            const float s4 = swzf<0x101F>(h);
            const float s5 = swzf<0x141F>(h);
            const float s6 = swzf<0x181F>(h);

            v2f aIF = pk_fma_b(wihIF[0], xt.x, biasIF);
            v2f bIF = pk_mul_b(wihIF[1], xt.y);
            v2f aGO = pk_fma_b(wihGO[0], xt.x, biasGO);
            v2f bGO = pk_mul_b(wihGO[1], xt.y);
            pk_fma_acc(aIF, wihIF[2], xt.z);  pk_fma_acc(bIF, wihIF[3], xt.w);
            pk_fma_acc(aGO, wihGO[2], xt.z);  pk_fma_acc(bGO, wihGO[3], xt.w);
            pk_fma_acc(aIF, whhIF[0], h);     pk_fma_acc(aGO, whhGO[0], h);
            pk_fma_acc(bIF, whhIF[1], s1);    pk_fma_acc(bGO, whhGO[1], s1);
            pk_fma_acc(aIF, whhIF[2], s2);    pk_fma_acc(aGO, whhGO[2], s2);
            pk_fma_acc(bIF, whhIF[3], s3);    pk_fma_acc(bGO, whhGO[3], s3);
            pk_fma_acc(aIF, whhIF[4], s4);    pk_fma_acc(aGO, whhGO[4], s4);
            pk_fma_acc(bIF, whhIF[5], s5);    pk_fma_acc(bGO, whhGO[5], s5);
            pk_fma_acc(aIF, whhIF[6], s6);    pk_fma_acc(aGO, whhGO[6], s6);
            pk_fma_acc(bIF, whhIF[7], s7);    pk_fma_acc(bGO, whhGO[7], s7);
            const v2f gIF = pk_add2(aIF, bIF);
            const v2f gGO = pk_add2(aGO, bGO);

            const float eI = __builtin_amdgcn_exp2f(nL  * gIF.x);
            const float eF = __builtin_amdgcn_exp2f(nL  * gIF.y);
            const float eG = __builtin_amdgcn_exp2f(n2L * gGO.x);
            const float eO = __builtin_amdgcn_exp2f(nL  * gGO.y);
            const float i_ = __builtin_amdgcn_rcpf(1.0f + eI);
            const float f_ = __builtin_amdgcn_rcpf(1.0f + eF);
            const float o_ = __builtin_amdgcn_rcpf(1.0f + eO);
            const float g_ = fmaf(__builtin_amdgcn_rcpf(1.0f + eG), 2.0f, -1.0f);

            c = fmaf(f_, c, i_ * g_);
            const float eC = __builtin_amdgcn_exp2f(n2L * c);
            h = o_ * fmaf(__builtin_amdgcn_rcpf(1.0f + eC), 2.0f, -1.0f);
        }
        __syncthreads();
    }

    // out = h . W_fc + b_fc, reduced over the 8-lane group
    float pr = h * W_fc[j];
    pr += __shfl_xor(pr, 1);
    pr += __shfl_xor(pr, 2);
    pr += __shfl_xor(pr, 4);
    if (j == 0) out[blockIdx.x * EPB + e] = pr + b_fc[0];
}

extern "C" void kernel_launch(void* const* d_in, const int* in_sizes, int n_in,
                              void* d_out, int out_size, void* d_ws, size_t ws_size,
                              hipStream_t stream) {
    const float* x    = (const float*)d_in[0];
    const float* W_ih = (const float*)d_in[1];
    const float* W_hh = (const float*)d_in[2];
    const float* b_ih = (const float*)d_in[3];
    const float* b_hh = (const float*)d_in[4];
    const float* W_fc = (const float*)d_in[5];
    const float* b_fc = (const float*)d_in[6];
    float* out = (float*)d_out;

    const int B = in_sizes[0] / (T_STEPS * 4);   // 8192
    const int block = 256;
    const int grid = (B * 8) / block;            // 256 blocks, 1 per CU
    lstm_kernel<<<grid, block, 0, stream>>>(x, W_ih, W_hh, b_ih, b_hh, W_fc, b_fc, out, B);
}

// Round 7
// 191.226 us; speedup vs baseline: 1.2120x; 1.2120x over previous
//
#include <hip/hip_runtime.h>

#define T_STEPS 512
#define CHUNK   32
#define NCHUNK  (T_STEPS / CHUNK)   // 16
#define EPB     32                  // elements per 256-thread block
#define ROWF    132                 // padded row: 33 float4 (xt reads bank-conflict-free)
#define BUFF    (EPB * ROWF)        // 4224 floats per buffer
#define LOG2E   1.4426950408889634f

typedef float v2f __attribute__((ext_vector_type(2)));

// Packed fp32 ops; scalar s broadcast from the LOW half of an undef-high pair
// via op_sel_hi (numerics verified R5/R6).
__device__ __forceinline__ v2f pk_fma_b(v2f w, float s, v2f c) {
    v2f sv; sv.x = s;
    v2f d;
    asm("v_pk_fma_f32 %0, %1, %2, %3 op_sel_hi:[1,0,1]"
        : "=v"(d) : "v"(w), "v"(sv), "v"(c));
    return d;
}
__device__ __forceinline__ void pk_fma_acc(v2f& a, v2f w, float s) {
    v2f sv; sv.x = s;
    asm("v_pk_fma_f32 %0, %1, %2, %0 op_sel_hi:[1,0,1]"
        : "+v"(a) : "v"(w), "v"(sv));
}
__device__ __forceinline__ v2f pk_mul_b(v2f w, float s) {
    v2f sv; sv.x = s;
    v2f d;
    asm("v_pk_mul_f32 %0, %1, %2 op_sel_hi:[1,0]"
        : "=v"(d) : "v"(w), "v"(sv));
    return d;
}
__device__ __forceinline__ v2f pk_add2(v2f a, v2f b) {
    v2f d;
    asm("v_pk_add_f32 %0, %1, %2" : "=v"(d) : "v"(a), "v"(b));
    return d;
}

// Cross-lane xor within the 8-lane group (all verified correct in R6):
//  xor1=quad_perm 0xB1, xor2=0x4E, xor3=0x1B, xor7=row_half_mirror 0x141 (DPP);
//  xor4/5/6 = ds_swizzle BitMode.
template <int CTRL>
__device__ __forceinline__ float dppf(float v) {
    return __int_as_float(__builtin_amdgcn_update_dpp(
        0, __float_as_int(v), CTRL, 0xF, 0xF, true));
}
template <int IMM>
__device__ __forceinline__ float swzf(float v) {
    return __int_as_float(__builtin_amdgcn_ds_swizzle(__float_as_int(v), IMM));
}

// 8 lanes per batch element; lane j owns unit j's 4 gate rows packed (i,f)/(g,o).
// R6 post-mortem: scratch spills (WRITE_SIZE 15 MB, VGPR=60) killed it. Fixes:
// plain __launch_bounds__(256) (33KB LDS caps occupancy at 4 blk/CU -> 128-VGPR
// budget), no address arrays (q-offsets are compile-time constants since
// 256%32==0), xc/xn software pipeline on the per-step LDS read.
__global__ __launch_bounds__(256) void lstm_kernel(
    const float* __restrict__ x, const float* __restrict__ W_ih,
    const float* __restrict__ W_hh, const float* __restrict__ b_ih,
    const float* __restrict__ b_hh, const float* __restrict__ W_fc,
    const float* __restrict__ b_fc, float* __restrict__ out, int B)
{
    __shared__ float ldsx[2 * BUFF];

    const int tid = threadIdx.x;
    const int e   = tid >> 3;          // block-local element [0,32)
    const int j   = tid & 7;           // hidden unit

    // ---- loop-invariant weights (packed gate pairs; W_hh xor-permuted) ----
    const int ri = j, rf = 8 + j, rg = 16 + j, ro = 24 + j;
    v2f wihIF[4], wihGO[4], whhIF[8], whhGO[8], biasIF, biasGO;
    #pragma unroll
    for (int k = 0; k < 4; ++k) {
        wihIF[k] = v2f{W_ih[ri * 4 + k], W_ih[rf * 4 + k]};
        wihGO[k] = v2f{W_ih[rg * 4 + k], W_ih[ro * 4 + k]};
    }
    #pragma unroll
    for (int s = 0; s < 8; ++s) {
        const int m = j ^ s;           // unit arriving via xor-s exchange
        whhIF[s] = v2f{W_hh[ri * 8 + m], W_hh[rf * 8 + m]};
        whhGO[s] = v2f{W_hh[rg * 8 + m], W_hh[ro * 8 + m]};
    }
    biasIF = v2f{b_ih[ri] + b_hh[ri], b_ih[rf] + b_hh[rf]};
    biasGO = v2f{b_ih[rg] + b_hh[rg], b_ih[ro] + b_hh[ro]};

    // ---- x staging: thread covers flat slots tid + q*256 (q=0..3).
    // st = tid&31 is q-invariant; element index advances by 8 per q, so the
    // q-th global/LDS addresses are base + constant offsets (no arrays).
    const int st  = tid & 31;              // step within chunk
    const int se0 = tid >> 5;              // first element this thread stages
    const float* gp0 = x + (size_t)(blockIdx.x * EPB + se0) * (T_STEPS * 4) + st * 4;
    const int wl0 = se0 * ROWF + st * 4;   // LDS float index, +q*8*ROWF per q

    float4 v0, v1, v2, v3;
    // chunk 0
    v0 = *(const float4*)(gp0);
    v1 = *(const float4*)(gp0 + 8 * 2048);
    v2 = *(const float4*)(gp0 + 16 * 2048);
    v3 = *(const float4*)(gp0 + 24 * 2048);
    *(float4*)&ldsx[wl0 + 0 * 8 * ROWF] = v0;
    *(float4*)&ldsx[wl0 + 1 * 8 * ROWF] = v1;
    *(float4*)&ldsx[wl0 + 2 * 8 * ROWF] = v2;
    *(float4*)&ldsx[wl0 + 3 * 8 * ROWF] = v3;
    // chunk 1 into regs
    v0 = *(const float4*)(gp0 + CHUNK * 4);
    v1 = *(const float4*)(gp0 + CHUNK * 4 + 8 * 2048);
    v2 = *(const float4*)(gp0 + CHUNK * 4 + 16 * 2048);
    v3 = *(const float4*)(gp0 + CHUNK * 4 + 24 * 2048);
    __syncthreads();

    float h = 0.0f, c = 0.0f;
    const float nL  = -LOG2E;
    const float n2L = -2.0f * LOG2E;

    for (int n = 0; n < NCHUNK; ++n) {
        // publish chunk n+1 (regs loaded one chunk ago — long since landed)
        const int wb = ((n + 1) & 1) * BUFF + wl0;
        *(float4*)&ldsx[wb + 0 * 8 * ROWF] = v0;
        *(float4*)&ldsx[wb + 1 * 8 * ROWF] = v1;
        *(float4*)&ldsx[wb + 2 * 8 * ROWF] = v2;
        *(float4*)&ldsx[wb + 3 * 8 * ROWF] = v3;
        // fetch chunk n+2 (wraps; junk on last iters, never consumed)
        const int t2 = ((n + 2) & (NCHUNK - 1)) * (CHUNK * 4);
        v0 = *(const float4*)(gp0 + t2);
        v1 = *(const float4*)(gp0 + t2 + 8 * 2048);
        v2 = *(const float4*)(gp0 + t2 + 16 * 2048);
        v3 = *(const float4*)(gp0 + t2 + 24 * 2048);

        const float* xr = &ldsx[(n & 1) * BUFF + e * ROWF];
        float4 xc = *(const float4*)(xr);     // step 0 of this chunk
        #pragma unroll
        for (int t = 0; t < CHUNK; ++t) {
            // prefetch next step's x (wraps to slot 0 on last iter; unused)
            const float4 xn = *(const float4*)(xr + (((t + 1) & (CHUNK - 1)) * 4));
            const float4 xt = xc;

            const float s1 = dppf<0xB1>(h);
            const float s2 = dppf<0x4E>(h);
            const float s3 = dppf<0x1B>(h);
            const float s7 = dppf<0x141>(h);
            const float s4 = swzf<0x101F>(h);
            const float s5 = swzf<0x141F>(h);
            const float s6 = swzf<0x181F>(h);

            v2f aIF = pk_fma_b(wihIF[0], xt.x, biasIF);
            v2f bIF = pk_mul_b(wihIF[1], xt.y);
            v2f aGO = pk_fma_b(wihGO[0], xt.x, biasGO);
            v2f bGO = pk_mul_b(wihGO[1], xt.y);
            pk_fma_acc(aIF, wihIF[2], xt.z);  pk_fma_acc(bIF, wihIF[3], xt.w);
            pk_fma_acc(aGO, wihGO[2], xt.z);  pk_fma_acc(bGO, wihGO[3], xt.w);
            pk_fma_acc(aIF, whhIF[0], h);     pk_fma_acc(aGO, whhGO[0], h);
            pk_fma_acc(bIF, whhIF[1], s1);    pk_fma_acc(bGO, whhGO[1], s1);
            pk_fma_acc(aIF, whhIF[2], s2);    pk_fma_acc(aGO, whhGO[2], s2);
            pk_fma_acc(bIF, whhIF[3], s3);    pk_fma_acc(bGO, whhGO[3], s3);
            pk_fma_acc(aIF, whhIF[4], s4);    pk_fma_acc(aGO, whhGO[4], s4);
            pk_fma_acc(bIF, whhIF[5], s5);    pk_fma_acc(bGO, whhGO[5], s5);
            pk_fma_acc(aIF, whhIF[6], s6);    pk_fma_acc(aGO, whhGO[6], s6);
            pk_fma_acc(bIF, whhIF[7], s7);    pk_fma_acc(bGO, whhGO[7], s7);
            const v2f gIF = pk_add2(aIF, bIF);
            const v2f gGO = pk_add2(aGO, bGO);

            const float eI = __builtin_amdgcn_exp2f(nL  * gIF.x);
            const float eF = __builtin_amdgcn_exp2f(nL  * gIF.y);
            const float eG = __builtin_amdgcn_exp2f(n2L * gGO.x);
            const float eO = __builtin_amdgcn_exp2f(nL  * gGO.y);
            const float i_ = __builtin_amdgcn_rcpf(1.0f + eI);
            const float f_ = __builtin_amdgcn_rcpf(1.0f + eF);
            const float o_ = __builtin_amdgcn_rcpf(1.0f + eO);
            const float g_ = fmaf(__builtin_amdgcn_rcpf(1.0f + eG), 2.0f, -1.0f);

            c = fmaf(f_, c, i_ * g_);
            const float eC = __builtin_amdgcn_exp2f(n2L * c);
            h = o_ * fmaf(__builtin_amdgcn_rcpf(1.0f + eC), 2.0f, -1.0f);
            xc = xn;
        }
        __syncthreads();
    }

    // out = h . W_fc + b_fc, reduced over the 8-lane group
    float pr = h * W_fc[j];
    pr += __shfl_xor(pr, 1);
    pr += __shfl_xor(pr, 2);
    pr += __shfl_xor(pr, 4);
    if (j == 0) out[blockIdx.x * EPB + e] = pr + b_fc[0];
}

extern "C" void kernel_launch(void* const* d_in, const int* in_sizes, int n_in,
                              void* d_out, int out_size, void* d_ws, size_t ws_size,
                              hipStream_t stream) {
    const float* x    = (const float*)d_in[0];
    const float* W_ih = (const float*)d_in[1];
    const float* W_hh = (const float*)d_in[2];
    const float* b_ih = (const float*)d_in[3];
    const float* b_hh = (const float*)d_in[4];
    const float* W_fc = (const float*)d_in[5];
    const float* b_fc = (const float*)d_in[6];
    float* out = (float*)d_out;

    const int B = in_sizes[0] / (T_STEPS * 4);   // 8192
    const int block = 256;
    const int grid = (B * 8) / block;            // 256 blocks
    lstm_kernel<<<grid, block, 0, stream>>>(x, W_ih, W_hh, b_ih, b_hh, W_fc, b_fc, out, B);
}

// Round 8
// 185.966 us; speedup vs baseline: 1.2463x; 1.0283x over previous
//
#include <hip/hip_runtime.h>

#define T_STEPS 512
#define CHUNK   32
#define NCHUNK  (T_STEPS / CHUNK)   // 16
#define EPB     32                  // elements per 256-thread block
#define ROWF    132                 // padded row: 33 float4 (xt reads bank-conflict-free)
#define BUFF    (EPB * ROWF)        // 4224 floats per buffer
#define LOG2E   1.4426950408889634f

typedef float v2f __attribute__((ext_vector_type(2)));

// Packed fp32 ops; scalar s broadcast from the LOW half of an undef-high pair
// via op_sel_hi (numerics verified R5-R7).
__device__ __forceinline__ v2f pk_fma_b(v2f w, float s, v2f c) {
    v2f sv; sv.x = s;
    v2f d;
    asm("v_pk_fma_f32 %0, %1, %2, %3 op_sel_hi:[1,0,1]"
        : "=v"(d) : "v"(w), "v"(sv), "v"(c));
    return d;
}
__device__ __forceinline__ void pk_fma_acc(v2f& a, v2f w, float s) {
    v2f sv; sv.x = s;
    asm("v_pk_fma_f32 %0, %1, %2, %0 op_sel_hi:[1,0,1]"
        : "+v"(a) : "v"(w), "v"(sv));
}
__device__ __forceinline__ v2f pk_mul_b(v2f w, float s) {
    v2f sv; sv.x = s;
    v2f d;
    asm("v_pk_mul_f32 %0, %1, %2 op_sel_hi:[1,0]"
        : "=v"(d) : "v"(w), "v"(sv));
    return d;
}
__device__ __forceinline__ v2f pk_add2(v2f a, v2f b) {
    v2f d;
    asm("v_pk_add_f32 %0, %1, %2" : "=v"(d) : "v"(a), "v"(b));
    return d;
}

// Cross-lane xor within the 8-lane group (verified R6/R7):
//  xor1=quad_perm 0xB1, xor2=0x4E, xor3=0x1B, xor7=row_half_mirror 0x141 (DPP);
//  xor4/5/6 = ds_swizzle BitMode.
template <int CTRL>
__device__ __forceinline__ float dppf(float v) {
    return __int_as_float(__builtin_amdgcn_update_dpp(
        0, __float_as_int(v), CTRL, 0xF, 0xF, true));
}
template <int IMM>
__device__ __forceinline__ float swzf(float v) {
    return __int_as_float(__builtin_amdgcn_ds_swizzle(__float_as_int(v), IMM));
}

// 8 lanes/elem; lane j owns unit j's 4 gate rows packed (i,f)/(g,o).
// R8 changes (trans is 60% of issue at ~16cyc/wave64-trans):
//  * exp2 scales folded into weights+biases at load: i/f/o rows x(-log2e),
//    g row x(-2log2e) -> exp2 eats accumulators directly (5 muls gone).
//  * exact rcp combining: i*g = (1-eG)/((1+eI)(1+eG)), h = o*tanh(c) =
//    (1-eC)/((1+eO)(1+eC)) -> 5 rcp -> 3 rcp per step.
//  * c kept pre-scaled (ct = -2log2e * c): eC = exp2(ct), scale folded into
//    the i*g numerator fma. Shorter serial tail.
//  * x-projection on its own accumulators, textually first (h-independent ->
//    schedulable into the previous step's trans tail).
__global__ __launch_bounds__(256) void lstm_kernel(
    const float* __restrict__ x, const float* __restrict__ W_ih,
    const float* __restrict__ W_hh, const float* __restrict__ b_ih,
    const float* __restrict__ b_hh, const float* __restrict__ W_fc,
    const float* __restrict__ b_fc, float* __restrict__ out, int B)
{
    __shared__ float ldsx[2 * BUFF];

    const int tid = threadIdx.x;
    const int e   = tid >> 3;          // block-local element [0,32)
    const int j   = tid & 7;           // hidden unit

    const float nL  = -LOG2E;          // scale for i,f,o rows
    const float n2L = -2.0f * LOG2E;   // scale for g row
    const float P2L =  2.0f * LOG2E;   // +2log2e (for the i*g numerator fma)

    // ---- loop-invariant weights (packed gate pairs; W_hh xor-permuted;
    //      exp2 arg scales pre-folded) ----
    const int ri = j, rf = 8 + j, rg = 16 + j, ro = 24 + j;
    v2f wihIF[4], wihGO[4], whhIF[8], whhGO[8], biasIF, biasGO;
    #pragma unroll
    for (int k = 0; k < 4; ++k) {
        wihIF[k] = v2f{nL  * W_ih[ri * 4 + k], nL * W_ih[rf * 4 + k]};
        wihGO[k] = v2f{n2L * W_ih[rg * 4 + k], nL * W_ih[ro * 4 + k]};
    }
    #pragma unroll
    for (int s = 0; s < 8; ++s) {
        const int m = j ^ s;           // unit arriving via xor-s exchange
        whhIF[s] = v2f{nL  * W_hh[ri * 8 + m], nL * W_hh[rf * 8 + m]};
        whhGO[s] = v2f{n2L * W_hh[rg * 8 + m], nL * W_hh[ro * 8 + m]};
    }
    biasIF = v2f{nL  * (b_ih[ri] + b_hh[ri]), nL * (b_ih[rf] + b_hh[rf])};
    biasGO = v2f{n2L * (b_ih[rg] + b_hh[rg]), nL * (b_ih[ro] + b_hh[ro])};

    // ---- x staging: thread covers flat slots tid + q*256 (q=0..3);
    // st = tid&31 is q-invariant -> q-offsets are compile-time constants.
    const int st  = tid & 31;              // step within chunk
    const int se0 = tid >> 5;              // first element this thread stages
    const float* gp0 = x + (size_t)(blockIdx.x * EPB + se0) * (T_STEPS * 4) + st * 4;
    const int wl0 = se0 * ROWF + st * 4;   // LDS float index, +q*8*ROWF per q

    float4 v0, v1, v2, v3;
    v0 = *(const float4*)(gp0);
    v1 = *(const float4*)(gp0 + 8 * 2048);
    v2 = *(const float4*)(gp0 + 16 * 2048);
    v3 = *(const float4*)(gp0 + 24 * 2048);
    *(float4*)&ldsx[wl0 + 0 * 8 * ROWF] = v0;
    *(float4*)&ldsx[wl0 + 1 * 8 * ROWF] = v1;
    *(float4*)&ldsx[wl0 + 2 * 8 * ROWF] = v2;
    *(float4*)&ldsx[wl0 + 3 * 8 * ROWF] = v3;
    v0 = *(const float4*)(gp0 + CHUNK * 4);
    v1 = *(const float4*)(gp0 + CHUNK * 4 + 8 * 2048);
    v2 = *(const float4*)(gp0 + CHUNK * 4 + 16 * 2048);
    v3 = *(const float4*)(gp0 + CHUNK * 4 + 24 * 2048);
    __syncthreads();

    float h = 0.0f, ct = 0.0f;         // ct = -2log2e * c (pre-scaled cell)

    for (int n = 0; n < NCHUNK; ++n) {
        // publish chunk n+1 (regs loaded one chunk ago — long since landed)
        const int wb = ((n + 1) & 1) * BUFF + wl0;
        *(float4*)&ldsx[wb + 0 * 8 * ROWF] = v0;
        *(float4*)&ldsx[wb + 1 * 8 * ROWF] = v1;
        *(float4*)&ldsx[wb + 2 * 8 * ROWF] = v2;
        *(float4*)&ldsx[wb + 3 * 8 * ROWF] = v3;
        // fetch chunk n+2 (wraps; junk on last iters, never consumed)
        const int t2 = ((n + 2) & (NCHUNK - 1)) * (CHUNK * 4);
        v0 = *(const float4*)(gp0 + t2);
        v1 = *(const float4*)(gp0 + t2 + 8 * 2048);
        v2 = *(const float4*)(gp0 + t2 + 16 * 2048);
        v3 = *(const float4*)(gp0 + t2 + 24 * 2048);

        const float* xr = &ldsx[(n & 1) * BUFF + e * ROWF];
        float4 xc = *(const float4*)(xr);     // step 0 of this chunk
        #pragma unroll
        for (int t = 0; t < CHUNK; ++t) {
            const float4 xn = *(const float4*)(xr + (((t + 1) & (CHUNK - 1)) * 4));
            const float4 xt = xc;

            // x-projection + bias: independent of h -> scheduler can hoist
            // these into the previous step's trans tail.
            v2f xIF = pk_fma_b(wihIF[0], xt.x, biasIF);
            v2f xGO = pk_fma_b(wihGO[0], xt.x, biasGO);
            pk_fma_acc(xIF, wihIF[1], xt.y);  pk_fma_acc(xGO, wihGO[1], xt.y);
            pk_fma_acc(xIF, wihIF[2], xt.z);  pk_fma_acc(xGO, wihGO[2], xt.z);
            pk_fma_acc(xIF, wihIF[3], xt.w);  pk_fma_acc(xGO, wihGO[3], xt.w);

            const float s1 = dppf<0xB1>(h);
            const float s2 = dppf<0x4E>(h);
            const float s3 = dppf<0x1B>(h);
            const float s7 = dppf<0x141>(h);
            const float s4 = swzf<0x101F>(h);
            const float s5 = swzf<0x141F>(h);
            const float s6 = swzf<0x181F>(h);

            v2f aIF = pk_mul_b(whhIF[0], h);
            v2f bIF = pk_mul_b(whhIF[1], s1);
            v2f aGO = pk_mul_b(whhGO[0], h);
            v2f bGO = pk_mul_b(whhGO[1], s1);
            pk_fma_acc(aIF, whhIF[2], s2);    pk_fma_acc(aGO, whhGO[2], s2);
            pk_fma_acc(bIF, whhIF[3], s3);    pk_fma_acc(bGO, whhGO[3], s3);
            pk_fma_acc(aIF, whhIF[4], s4);    pk_fma_acc(aGO, whhGO[4], s4);
            pk_fma_acc(bIF, whhIF[5], s5);    pk_fma_acc(bGO, whhGO[5], s5);
            pk_fma_acc(aIF, whhIF[6], s6);    pk_fma_acc(aGO, whhGO[6], s6);
            pk_fma_acc(bIF, whhIF[7], s7);    pk_fma_acc(bGO, whhGO[7], s7);
            const v2f gIF = pk_add2(pk_add2(aIF, xIF), bIF);  // (ãi, ãf)
            const v2f gGO = pk_add2(pk_add2(aGO, xGO), bGO);  // (ãg, ão)

            // eX = exp(-aX) (i,f,o) / exp(-2*ag) (g) — args pre-scaled
            const float eI = __builtin_amdgcn_exp2f(gIF.x);
            const float eF = __builtin_amdgcn_exp2f(gIF.y);
            const float eG = __builtin_amdgcn_exp2f(gGO.x);
            const float eO = __builtin_amdgcn_exp2f(gGO.y);

            const float R  = __builtin_amdgcn_rcpf((1.0f + eI) * (1.0f + eG));
            const float f_ = __builtin_amdgcn_rcpf(1.0f + eF);
            const float ign = fmaf(eG, P2L, n2L) * R;   // -2log2e * i * g
            ct = fmaf(f_, ct, ign);                     // scaled cell update
            const float eC = __builtin_amdgcn_exp2f(ct);
            const float RC = __builtin_amdgcn_rcpf((1.0f + eO) * (1.0f + eC));
            h = (1.0f - eC) * RC;                       // o * tanh(c)

            xc = xn;
        }
        __syncthreads();
    }

    // out = h . W_fc + b_fc, reduced over the 8-lane group
    float pr = h * W_fc[j];
    pr += __shfl_xor(pr, 1);
    pr += __shfl_xor(pr, 2);
    pr += __shfl_xor(pr, 4);
    if (j == 0) out[blockIdx.x * EPB + e] = pr + b_fc[0];
}

extern "C" void kernel_launch(void* const* d_in, const int* in_sizes, int n_in,
                              void* d_out, int out_size, void* d_ws, size_t ws_size,
                              hipStream_t stream) {
    const float* x    = (const float*)d_in[0];
    const float* W_ih = (const float*)d_in[1];
    const float* W_hh = (const float*)d_in[2];
    const float* b_ih = (const float*)d_in[3];
    const float* b_hh = (const float*)d_in[4];
    const float* W_fc = (const float*)d_in[5];
    const float* b_fc = (const float*)d_in[6];
    float* out = (float*)d_out;

    const int B = in_sizes[0] / (T_STEPS * 4);   // 8192
    const int block = 256;
    const int grid = (B * 8) / block;            // 256 blocks
    lstm_kernel<<<grid, block, 0, stream>>>(x, W_ih, W_hh, b_ih, b_hh, W_fc, b_fc, out, B);
}

// Round 9
// 172.920 us; speedup vs baseline: 1.3403x; 1.0754x over previous
//
#include <hip/hip_runtime.h>

#define T_STEPS 512
#define CHUNK   32
#define NCHUNK  (T_STEPS / CHUNK)   // 16
#define EPB     32                  // elements per 256-thread block
#define ROWF    132                 // padded row: 33 float4 (xt reads bank-conflict-free)
#define BUFF    (EPB * ROWF)        // 4224 floats per buffer
#define LOG2E   1.4426950408889634f

typedef float v2f __attribute__((ext_vector_type(2)));

// Packed fp32 ops; scalar s broadcast from the LOW half of an undef-high pair
// via op_sel_hi (numerics verified R5-R8).
__device__ __forceinline__ v2f pk_fma_b(v2f w, float s, v2f c) {
    v2f sv; sv.x = s;
    v2f d;
    asm("v_pk_fma_f32 %0, %1, %2, %3 op_sel_hi:[1,0,1]"
        : "=v"(d) : "v"(w), "v"(sv), "v"(c));
    return d;
}
__device__ __forceinline__ void pk_fma_acc(v2f& a, v2f w, float s) {
    v2f sv; sv.x = s;
    asm("v_pk_fma_f32 %0, %1, %2, %0 op_sel_hi:[1,0,1]"
        : "+v"(a) : "v"(w), "v"(sv));
}
__device__ __forceinline__ v2f pk_mul_b(v2f w, float s) {
    v2f sv; sv.x = s;
    v2f d;
    asm("v_pk_mul_f32 %0, %1, %2 op_sel_hi:[1,0]"
        : "=v"(d) : "v"(w), "v"(sv));
    return d;
}
__device__ __forceinline__ v2f pk_add2(v2f a, v2f b) {
    v2f d;
    asm("v_pk_add_f32 %0, %1, %2" : "=v"(d) : "v"(a), "v"(b));
    return d;
}

// Cross-lane xor within the 8-lane group — ALL DPP now (R9):
//  xor1=quad_perm 0xB1, xor2=0x4E, xor3=0x1B, xor7=row_half_mirror 0x141.
//  xor4/5/6 composed as xorK = xor(K^7) applied to s7 (xor is a group):
//  s4=qp<0x1B>(s7), s5=qp<0x4E>(s7), s6=qp<0xB1>(s7). Zero LDS-pipe ops in
//  the recurrence chain -> no per-step lgkmcnt stalls (R8's hidden cost).
template <int CTRL>
__device__ __forceinline__ float dppf(float v) {
    return __int_as_float(__builtin_amdgcn_update_dpp(
        0, __float_as_int(v), CTRL, 0xF, 0xF, true));
}

// 8 lanes/elem; lane j owns unit j's 4 gate rows packed (i,f)/(g,o).
// exp2 scales pre-folded into weights (i/f/o x -log2e, g x -2log2e);
// rcp-combined activations: i*g = (1-eG)/((1+eI)(1+eG)),
// h = (1-eC)/((1+eO)(1+eC)); cell kept pre-scaled ct = -2log2e*c.
__global__ __launch_bounds__(256) void lstm_kernel(
    const float* __restrict__ x, const float* __restrict__ W_ih,
    const float* __restrict__ W_hh, const float* __restrict__ b_ih,
    const float* __restrict__ b_hh, const float* __restrict__ W_fc,
    const float* __restrict__ b_fc, float* __restrict__ out, int B)
{
    __shared__ float ldsx[2 * BUFF];

    const int tid = threadIdx.x;
    const int e   = tid >> 3;          // block-local element [0,32)
    const int j   = tid & 7;           // hidden unit

    const float nL  = -LOG2E;          // scale for i,f,o rows
    const float n2L = -2.0f * LOG2E;   // scale for g row
    const float P2L =  2.0f * LOG2E;

    // ---- loop-invariant weights (packed gate pairs; W_hh xor-permuted;
    //      exp2 arg scales pre-folded) ----
    const int ri = j, rf = 8 + j, rg = 16 + j, ro = 24 + j;
    v2f wihIF[4], wihGO[4], whhIF[8], whhGO[8], biasIF, biasGO;
    #pragma unroll
    for (int k = 0; k < 4; ++k) {
        wihIF[k] = v2f{nL  * W_ih[ri * 4 + k], nL * W_ih[rf * 4 + k]};
        wihGO[k] = v2f{n2L * W_ih[rg * 4 + k], nL * W_ih[ro * 4 + k]};
    }
    #pragma unroll
    for (int s = 0; s < 8; ++s) {
        const int m = j ^ s;           // unit arriving via xor-s exchange
        whhIF[s] = v2f{nL  * W_hh[ri * 8 + m], nL * W_hh[rf * 8 + m]};
        whhGO[s] = v2f{n2L * W_hh[rg * 8 + m], nL * W_hh[ro * 8 + m]};
    }
    biasIF = v2f{nL  * (b_ih[ri] + b_hh[ri]), nL * (b_ih[rf] + b_hh[rf])};
    biasGO = v2f{n2L * (b_ih[rg] + b_hh[rg]), nL * (b_ih[ro] + b_hh[ro])};

    // ---- x staging: thread covers flat slots tid + q*256 (q=0..3);
    // st = tid&31 is q-invariant -> q-offsets are compile-time constants.
    const int st  = tid & 31;              // step within chunk
    const int se0 = tid >> 5;              // first element this thread stages
    const float* gp0 = x + (size_t)(blockIdx.x * EPB + se0) * (T_STEPS * 4) + st * 4;
    const int wl0 = se0 * ROWF + st * 4;   // LDS float index, +q*8*ROWF per q

    float4 v0, v1, v2, v3;
    v0 = *(const float4*)(gp0);
    v1 = *(const float4*)(gp0 + 8 * 2048);
    v2 = *(const float4*)(gp0 + 16 * 2048);
    v3 = *(const float4*)(gp0 + 24 * 2048);
    *(float4*)&ldsx[wl0 + 0 * 8 * ROWF] = v0;
    *(float4*)&ldsx[wl0 + 1 * 8 * ROWF] = v1;
    *(float4*)&ldsx[wl0 + 2 * 8 * ROWF] = v2;
    *(float4*)&ldsx[wl0 + 3 * 8 * ROWF] = v3;
    v0 = *(const float4*)(gp0 + CHUNK * 4);
    v1 = *(const float4*)(gp0 + CHUNK * 4 + 8 * 2048);
    v2 = *(const float4*)(gp0 + CHUNK * 4 + 16 * 2048);
    v3 = *(const float4*)(gp0 + CHUNK * 4 + 24 * 2048);
    __syncthreads();

    float h = 0.0f, ct = 0.0f;         // ct = -2log2e * c (pre-scaled cell)

    for (int n = 0; n < NCHUNK; ++n) {
        // publish chunk n+1 (regs loaded one chunk ago — long since landed)
        const int wb = ((n + 1) & 1) * BUFF + wl0;
        *(float4*)&ldsx[wb + 0 * 8 * ROWF] = v0;
        *(float4*)&ldsx[wb + 1 * 8 * ROWF] = v1;
        *(float4*)&ldsx[wb + 2 * 8 * ROWF] = v2;
        *(float4*)&ldsx[wb + 3 * 8 * ROWF] = v3;
        // fetch chunk n+2 (wraps; junk on last iters, never consumed)
        const int t2 = ((n + 2) & (NCHUNK - 1)) * (CHUNK * 4);
        v0 = *(const float4*)(gp0 + t2);
        v1 = *(const float4*)(gp0 + t2 + 8 * 2048);
        v2 = *(const float4*)(gp0 + t2 + 16 * 2048);
        v3 = *(const float4*)(gp0 + t2 + 24 * 2048);

        const float* xr = &ldsx[(n & 1) * BUFF + e * ROWF];
        float4 xc = *(const float4*)(xr);     // step 0 of this chunk
        #pragma unroll
        for (int t = 0; t < CHUNK; ++t) {
            const float4 xn = *(const float4*)(xr + (((t + 1) & (CHUNK - 1)) * 4));
            const float4 xt = xc;

            // x-projection + bias: h-independent -> fills the previous step's
            // trans tail.
            v2f xIF = pk_fma_b(wihIF[0], xt.x, biasIF);
            v2f xGO = pk_fma_b(wihGO[0], xt.x, biasGO);
            pk_fma_acc(xIF, wihIF[1], xt.y);  pk_fma_acc(xGO, wihGO[1], xt.y);
            pk_fma_acc(xIF, wihIF[2], xt.z);  pk_fma_acc(xGO, wihGO[2], xt.z);
            pk_fma_acc(xIF, wihIF[3], xt.w);  pk_fma_acc(xGO, wihGO[3], xt.w);

            // all-DPP h exchange (depth 2)
            const float s1 = dppf<0xB1>(h);
            const float s2 = dppf<0x4E>(h);
            const float s3 = dppf<0x1B>(h);
            const float s7 = dppf<0x141>(h);
            const float s4 = dppf<0x1B>(s7);   // xor3 o xor7 = xor4
            const float s5 = dppf<0x4E>(s7);   // xor2 o xor7 = xor5
            const float s6 = dppf<0xB1>(s7);   // xor1 o xor7 = xor6

            // h-projection, x-projection folded into chain heads
            v2f aIF = pk_fma_b(whhIF[0], h,  xIF);
            v2f bIF = pk_mul_b(whhIF[1], s1);
            v2f aGO = pk_fma_b(whhGO[0], h,  xGO);
            v2f bGO = pk_mul_b(whhGO[1], s1);
            pk_fma_acc(aIF, whhIF[2], s2);    pk_fma_acc(aGO, whhGO[2], s2);
            pk_fma_acc(bIF, whhIF[3], s3);    pk_fma_acc(bGO, whhGO[3], s3);
            pk_fma_acc(aIF, whhIF[4], s4);    pk_fma_acc(aGO, whhGO[4], s4);
            pk_fma_acc(bIF, whhIF[5], s5);    pk_fma_acc(bGO, whhGO[5], s5);
            pk_fma_acc(aIF, whhIF[6], s6);    pk_fma_acc(aGO, whhGO[6], s6);
            pk_fma_acc(bIF, whhIF[7], s7);    pk_fma_acc(bGO, whhGO[7], s7);
            const v2f gIF = pk_add2(aIF, bIF);  // (ãi, ãf)
            const v2f gGO = pk_add2(aGO, bGO);  // (ãg, ão)

            // eX = exp(-aX) (i,f,o) / exp(-2*ag) (g) — args pre-scaled
            const float eI = __builtin_amdgcn_exp2f(gIF.x);
            const float eF = __builtin_amdgcn_exp2f(gIF.y);
            const float eG = __builtin_amdgcn_exp2f(gGO.x);
            const float eO = __builtin_amdgcn_exp2f(gGO.y);

            const float R  = __builtin_amdgcn_rcpf((1.0f + eI) * (1.0f + eG));
            const float f_ = __builtin_amdgcn_rcpf(1.0f + eF);
            const float ign = fmaf(eG, P2L, n2L) * R;   // -2log2e * i * g
            ct = fmaf(f_, ct, ign);                     // scaled cell update
            const float eC = __builtin_amdgcn_exp2f(ct);
            const float RC = __builtin_amdgcn_rcpf((1.0f + eO) * (1.0f + eC));
            h = (1.0f - eC) * RC;                       // o * tanh(c)

            xc = xn;
        }
        __syncthreads();
    }

    // out = h . W_fc + b_fc, reduced over the 8-lane group
    float pr = h * W_fc[j];
    pr += __shfl_xor(pr, 1);
    pr += __shfl_xor(pr, 2);
    pr += __shfl_xor(pr, 4);
    if (j == 0) out[blockIdx.x * EPB + e] = pr + b_fc[0];
}

extern "C" void kernel_launch(void* const* d_in, const int* in_sizes, int n_in,
                              void* d_out, int out_size, void* d_ws, size_t ws_size,
                              hipStream_t stream) {
    const float* x    = (const float*)d_in[0];
    const float* W_ih = (const float*)d_in[1];
    const float* W_hh = (const float*)d_in[2];
    const float* b_ih = (const float*)d_in[3];
    const float* b_hh = (const float*)d_in[4];
    const float* W_fc = (const float*)d_in[5];
    const float* b_fc = (const float*)d_in[6];
    float* out = (float*)d_out;

    const int B = in_sizes[0] / (T_STEPS * 4);   // 8192
    const int block = 256;
    const int grid = (B * 8) / block;            // 256 blocks
    lstm_kernel<<<grid, block, 0, stream>>>(x, W_ih, W_hh, b_ih, b_hh, W_fc, b_fc, out, B);
}